// Round 4
// baseline (528.492 us; speedup 1.0000x reference)
//
#include <hip/hip_runtime.h>
#include <hip/hip_bf16.h>

#define KK 50      // triples per (b,t)
#define DD 100
#define TWO_D 200
#define DPAD 112   // padded output-feature dim (7 * 16)
#define KHT 224    // padded K for head_tail gemm: [head pad 112 | tail pad 112]
#define KRL 128    // padded K for relation gemm (4 * 32)

// workspace layout (bytes)
#define WS_FLAGS 0
#define WS_WHT 256                       // bf16[DPAD*KHT]  = 50176 B
#define WS_WRL (WS_WHT + DPAD*KHT*2)     // bf16[DPAD*KRL]  = 28672 B
#define WS_BHT (WS_WRL + DPAD*KRL*2)     // bf16[DPAD] (256 B slot)
#define WS_BRL (WS_BHT + 256)

typedef __attribute__((ext_vector_type(8))) short   s8v;
typedef __attribute__((ext_vector_type(8))) __bf16  b8v;
typedef __attribute__((ext_vector_type(4))) float   f32x4;

// --- MFMA shim: tolerate either builtin signature (short8 or bf16x8 operands) ---
template <typename T>
__device__ __forceinline__ auto mfma_try(T a, T b, f32x4 c, int)
    -> decltype(__builtin_amdgcn_mfma_f32_16x16x32_bf16(a, b, c, 0, 0, 0)) {
    return __builtin_amdgcn_mfma_f32_16x16x32_bf16(a, b, c, 0, 0, 0);
}
template <typename T, typename U = b8v>
__device__ __forceinline__ f32x4 mfma_try(T a, T b, f32x4 c, long) {
    U ab = __builtin_bit_cast(U, a);
    U bb = __builtin_bit_cast(U, b);
    return __builtin_amdgcn_mfma_f32_16x16x32_bf16(ab, bb, c, 0, 0, 0);
}
__device__ __forceinline__ f32x4 mfma16x16x32_bf16(s8v a, s8v b, f32x4 c) {
    return mfma_try(a, b, c, 0);
}

__device__ __forceinline__ float bf2f(__hip_bfloat16 h) { return __bfloat162float(h); }

__device__ __forceinline__ float tanh_fast(float x) {
    // tanh(x) = 1 - 2/(exp(2x)+1); exp->inf -> rcp=0 -> 1; exp->0 -> -1; tanh(0)=0 exact.
    float e = __expf(2.f * x);
    return 1.f - 2.f * __builtin_amdgcn_rcpf(e + 1.f);
}

// ---------- dtype detection (wave-parallel: ~5 loads/lane, ballot reduce) ----------
__global__ void detect_dtypes(const unsigned int* __restrict__ emb_raw,
                              const unsigned int* __restrict__ ids_raw,
                              int* __restrict__ flags) {
    const int lane = threadIdx.x;   // 64 threads, 1 block
    int f32 = 0;
    #pragma unroll
    for (int rep = 0; rep < 4; rep++) {
        unsigned int w = emb_raw[lane + rep * 64];
        unsigned int e0 = (w >> 7)  & 0xFF;
        unsigned int e1 = (w >> 23) & 0xFF;
        if (e0 >= 0x87 || e1 >= 0x87) f32 = 1;   // |x| >= 256 impossible for real data
    }
    unsigned long long mf = __ballot(f32 != 0);
    unsigned long long mz = __ballot(ids_raw[2 * lane + 1] == 0u);
    if (lane == 0) {
        flags[0] = mf ? 1 : 0;
        flags[1] = (__popcll(mz) >= 32) ? 1 : 0;
    }
}

// ---------- canonicalize weights into zero-padded bf16 tiles in workspace ----------
// ht feature axis RE-PACKED: k<112 -> head feature k (k<100, else 0);
//                            k>=112 -> tail feature k-112 ((k-112)<100, else 0).
// This matches the direct-from-global A-fragment packing in the fused kernel.
__global__ void prep_weights(const void* __restrict__ Wht, const void* __restrict__ bht,
                             const void* __restrict__ Wrl, const void* __restrict__ brl,
                             void* __restrict__ ws) {
    const int* flags = (const int*)ws;
    const bool f32 = flags[0] != 0;
    __hip_bfloat16* whtp = (__hip_bfloat16*)((char*)ws + WS_WHT);
    __hip_bfloat16* wrlp = (__hip_bfloat16*)((char*)ws + WS_WRL);
    __hip_bfloat16* bhtp = (__hip_bfloat16*)((char*)ws + WS_BHT);
    __hip_bfloat16* brlp = (__hip_bfloat16*)((char*)ws + WS_BRL);

    const int gid = blockIdx.x * blockDim.x + threadIdx.x;
    const int gs  = gridDim.x * blockDim.x;

    for (int i = gid; i < DPAD * KHT; i += gs) {
        int d = i / KHT, f = i - d * KHT;
        int src = -1;
        if (f < 112) { if (f < DD) src = f; }                // head region
        else { int t = f - 112; if (t < DD) src = DD + t; }  // tail region
        float v = 0.f;
        if (d < DD && src >= 0)
            v = f32 ? ((const float*)Wht)[d * TWO_D + src]
                    : bf2f(((const __hip_bfloat16*)Wht)[d * TWO_D + src]);
        whtp[i] = __float2bfloat16(v);
    }
    for (int i = gid; i < DPAD * KRL; i += gs) {
        int d = i / KRL, f = i - d * KRL;
        float v = 0.f;
        if (d < DD && f < DD)
            v = f32 ? ((const float*)Wrl)[d * DD + f]
                    : bf2f(((const __hip_bfloat16*)Wrl)[d * DD + f]);
        wrlp[i] = __float2bfloat16(v);
    }
    for (int i = gid; i < DPAD; i += gs) {
        float vh = 0.f, vr = 0.f;
        if (i < DD) {
            vh = f32 ? ((const float*)bht)[i] : bf2f(((const __hip_bfloat16*)bht)[i]);
            vr = f32 ? ((const float*)brl)[i] : bf2f(((const __hip_bfloat16*)brl)[i]);
        }
        bhtp[i] = __float2bfloat16(vh);
        brlp[i] = __float2bfloat16(vr);
    }
}

// ---------- direct global->VGPR A-fragment chunk load (8 bf16 = one k-slice) ----------
// Loads emb[id][off..off+7] with per-half masks (exec-masked: inactive lanes
// never form the address, so no OOB). Returns bf16x8 as s8v.
template <bool F32>
__device__ __forceinline__ s8v load8(const void* __restrict__ emb, int id, int off,
                                     bool mL, bool mH) {
    const size_t base = (size_t)id * DD;
    if constexpr (F32) {
        const float* p = (const float*)emb + base;
        float4 lo = make_float4(0.f, 0.f, 0.f, 0.f);
        float4 hi = make_float4(0.f, 0.f, 0.f, 0.f);
        if (mL) lo = *(const float4*)(p + off);        // 16B aligned (row = 400B)
        if (mH) hi = *(const float4*)(p + off + 4);
        b8v a = { (__bf16)lo.x, (__bf16)lo.y, (__bf16)lo.z, (__bf16)lo.w,
                  (__bf16)hi.x, (__bf16)hi.y, (__bf16)hi.z, (__bf16)hi.w };
        return __builtin_bit_cast(s8v, a);
    } else {
        const __hip_bfloat16* p = (const __hip_bfloat16*)emb + base;
        uint2 lo = make_uint2(0u, 0u);
        uint2 hi = make_uint2(0u, 0u);
        if (mL) lo = *(const uint2*)(p + off);         // 8B aligned (row = 200B)
        if (mH) hi = *(const uint2*)(p + off + 4);
        struct P { uint2 a, b; } pk{lo, hi};
        return __builtin_bit_cast(s8v, pk);
    }
}

// ---------- the whole per-(b,t) computation, templated on emb dtype ----------
template <bool F32>
__device__ __forceinline__ void encoder_body(
    const void* __restrict__ emb_raw, const void* __restrict__ ws,
    float* __restrict__ out, const int* __restrict__ sIds,
    float* __restrict__ sE, float* __restrict__ sAl, int tid, int bt) {

    const __hip_bfloat16* whtp = (const __hip_bfloat16*)((const char*)ws + WS_WHT);
    const __hip_bfloat16* wrlp = (const __hip_bfloat16*)((const char*)ws + WS_WRL);
    const __hip_bfloat16* bhtp = (const __hip_bfloat16*)((const char*)ws + WS_BHT);
    const __hip_bfloat16* brlp = (const __hip_bfloat16*)((const char*)ws + WS_BRL);

    const int lane = tid & 63;
    const int w    = tid >> 6;        // wave id: rows [w*16, w*16+16)
    const int n    = lane & 15;       // A row / B col selector
    const int q    = lane >> 4;       // quad: k-slice q*8 within the 32-k window
    const int arow = w * 16 + n;
    const int arc  = (arow < KK) ? arow : 0;   // clamp: rows >= KK are don't-care

    const int id_h = sIds[arc * 3 + 0];
    const int id_r = sIds[arc * 3 + 1];
    const int id_t = sIds[arc * 3 + 2];

    // ---- head_tail GEMM: K packed [head(100)+pad12 | tail(100)+pad12] = 224 ----
    // chunk c = ks*4+q in [0,28): c<=11 full head, c==12 half head, c==13 zero,
    // 14<=c<=25 full tail, c==26 half tail, c==27 zero.
    f32x4 accH[7];
    #pragma unroll
    for (int t = 0; t < 7; t++) {
        #pragma unroll
        for (int j = 0; j < 4; j++) accH[t][j] = 0.f;
    }
    #pragma unroll
    for (int ks = 0; ks < 7; ks++) {
        const int  c       = ks * 4 + q;
        const bool is_head = (c < 13);
        const bool zer     = (c == 13) | (c == 27);
        const bool half    = (c == 12) | (c == 26);
        const int  off     = (is_head ? c : (c - 14)) * 8;
        const int  id      = is_head ? id_h : id_t;
        s8v a = load8<F32>(emb_raw, id, off, !zer, !(zer | half));
        #pragma unroll
        for (int nt = 0; nt < 7; nt++) {
            s8v b = *(const s8v*)(whtp + (nt * 16 + n) * KHT + ks * 32 + q * 8);
            accH[nt] = mfma16x16x32_bf16(a, b, accH[nt]);
        }
    }

    // bias + tanh (padded d: acc=0, bias=0 -> tanh(0)=0 -> zero contribution)
    float htv[7][4];
    #pragma unroll
    for (int nt = 0; nt < 7; nt++) {
        const float bias = bf2f(bhtp[nt * 16 + n]);
        #pragma unroll
        for (int j = 0; j < 4; j++) htv[nt][j] = tanh_fast(accH[nt][j] + bias);
    }

    // ---- relation GEMM: K=128; chunk c=ks*4+q: c<=11 full, c==12 half, >=13 zero ----
    f32x4 accR[7];
    #pragma unroll
    for (int t = 0; t < 7; t++) {
        #pragma unroll
        for (int j = 0; j < 4; j++) accR[t][j] = 0.f;
    }
    #pragma unroll
    for (int ks = 0; ks < 4; ks++) {
        const int  c    = ks * 4 + q;
        const bool zer  = (c >= 13);
        const bool half = (c == 12);
        const int  off  = (c <= 12 ? c : 0) * 8;
        s8v a = load8<F32>(emb_raw, id_r, off, !zer, !(zer | half));
        #pragma unroll
        for (int nt = 0; nt < 7; nt++) {
            s8v b = *(const s8v*)(wrlp + (nt * 16 + n) * KRL + ks * 32 + q * 8);
            accR[nt] = mfma16x16x32_bf16(a, b, accR[nt]);
        }
    }

    // ---- e_weight: rowwise dot(rel_t, ht_t); reduce over the 16 n-lanes ----
    float dj[4];
    #pragma unroll
    for (int j = 0; j < 4; j++) dj[j] = 0.f;
    #pragma unroll
    for (int nt = 0; nt < 7; nt++) {
        const float bias = bf2f(brlp[nt * 16 + n]);
        #pragma unroll
        for (int j = 0; j < 4; j++) dj[j] += (accR[nt][j] + bias) * htv[nt][j];
    }
    #pragma unroll
    for (int mask = 1; mask < 16; mask <<= 1) {
        #pragma unroll
        for (int j = 0; j < 4; j++) dj[j] += __shfl_xor(dj[j], mask, 64);
    }
    if (n == 0) {
        #pragma unroll
        for (int j = 0; j < 4; j++) {
            const int kt = w * 16 + q * 4 + j;   // C/D row = quad*4 + reg
            if (kt < KK) sE[kt] = dj[j];
        }
    }
    __syncthreads();

    // ---- softmax over KK triples (wave 0) ----
    if (tid < 64) {
        float v = (tid < KK) ? sE[tid] : -3.0e38f;
        float mx = v;
        #pragma unroll
        for (int mask = 1; mask < 64; mask <<= 1) mx = fmaxf(mx, __shfl_xor(mx, mask, 64));
        float p = (tid < KK) ? __expf(v - mx) : 0.f;
        float s = p;
        #pragma unroll
        for (int mask = 1; mask < 64; mask <<= 1) s += __shfl_xor(s, mask, 64);
        if (tid < KK) sAl[tid] = p / s;
    }
    __syncthreads();

    // ---- output (fp32): out[bt][d] = sum_k alpha[k] * head_tail[k][d] ----
    // Gather from global emb in full fp32 precision (rows are L2-hot: this
    // block just read them). d<100 -> head row, d>=100 -> tail row.
    if (tid < TWO_D) {
        const int half  = tid / DD;            // 0=head, 1=tail
        const int dmod  = tid - half * DD;
        const int whoff = half ? 2 : 0;
        float acc = 0.f;
        if constexpr (F32) {
            const float* embf = (const float*)emb_raw;
            #pragma unroll 10
            for (int k = 0; k < KK; k++) {
                size_t id = (size_t)sIds[k * 3 + whoff];
                acc += sAl[k] * embf[id * DD + dmod];
            }
        } else {
            const __hip_bfloat16* embh = (const __hip_bfloat16*)emb_raw;
            #pragma unroll 10
            for (int k = 0; k < KK; k++) {
                size_t id = (size_t)sIds[k * 3 + whoff];
                acc += sAl[k] * bf2f(embh[id * DD + dmod]);
            }
        }
        out[(size_t)bt * TWO_D + tid] = acc;
    }
}

__global__ __launch_bounds__(256, 5) void fused_outer_encoder(
    const int* __restrict__ ids,              // int32 or int64 (flagged)
    const void* __restrict__ emb_raw,         // fp32 or bf16 (flagged), [V][DD]
    const void* __restrict__ ws,
    float* __restrict__ out)                  // [NBT][TWO_D] fp32
{
    __shared__ int   sIds[KK * 3];
    __shared__ float sE[64];
    __shared__ float sAl[KK];

    const int* flags = (const int*)ws;
    const int tid = threadIdx.x;
    const int bt  = blockIdx.x;
    const bool f32      = flags[0] != 0;
    const int idsStride = flags[1] ? 2 : 1;   // int64: read low word

    if (tid < KK * 3) sIds[tid] = ids[(bt * (KK * 3) + tid) * idsStride];
    __syncthreads();

    if (f32) encoder_body<true >(emb_raw, ws, out, sIds, sE, sAl, tid, bt);
    else     encoder_body<false>(emb_raw, ws, out, sIds, sE, sAl, tid, bt);
}

extern "C" void kernel_launch(void* const* d_in, const int* in_sizes, int n_in,
                              void* d_out, int out_size, void* d_ws, size_t ws_size,
                              hipStream_t stream) {
    const int*  ids = (const int*)d_in[1];
    const void* emb = d_in[3];
    const void* Wht = d_in[4];
    const void* bht = d_in[5];
    const void* Wrl = d_in[6];
    const void* brl = d_in[7];
    float* out = (float*)d_out;

    const int nbt = in_sizes[1] / (KK * 3);   // B*T blocks

    hipLaunchKernelGGL(detect_dtypes, dim3(1), dim3(64), 0, stream,
                       (const unsigned int*)emb, (const unsigned int*)ids, (int*)d_ws);
    hipLaunchKernelGGL(prep_weights, dim3(64), dim3(256), 0, stream,
                       Wht, bht, Wrl, brl, d_ws);
    hipLaunchKernelGGL(fused_outer_encoder, dim3(nbt), dim3(256), 0, stream,
                       ids, emb, (const void*)d_ws, out);
}

// Round 5
// 512.433 us; speedup vs baseline: 1.0313x; 1.0313x over previous
//
#include <hip/hip_runtime.h>
#include <hip/hip_bf16.h>

#define KK 50      // triples per (b,t)
#define DD 100
#define TWO_D 200
#define DPAD 112   // padded output-feature dim (7 * 16)
#define KHT 224    // padded K for head_tail gemm: [head pad 112 | tail pad 112]
#define KRL 128    // padded K for relation gemm (4 * 32)

#define NROWS 150          // 50 triples * {head, rel, tail}
#define ROWP 104           // LDS row pitch in bf16 elems (16B-aligned rows, 4-elem pad)
#define SX_ELEMS ((NROWS + 1) * ROWP)   // +1 zeroed dummy row (overrun target for last row)

#define NCHUNK (NROWS * 25)   // 3750 4-elem gather chunks per block

// workspace layout (bytes)
#define WS_FLAGS 0
#define WS_WHT 256                       // bf16[DPAD*KHT]  = 50176 B
#define WS_WRL (WS_WHT + DPAD*KHT*2)     // bf16[DPAD*KRL]  = 28672 B
#define WS_BHT (WS_WRL + DPAD*KRL*2)     // bf16[DPAD] (256 B slot)
#define WS_BRL (WS_BHT + 256)

typedef __attribute__((ext_vector_type(8))) short   s8v;
typedef __attribute__((ext_vector_type(8))) __bf16  b8v;
typedef __attribute__((ext_vector_type(4))) __bf16  b4v;
typedef __attribute__((ext_vector_type(4))) float   f32x4;

// --- MFMA shim: tolerate either builtin signature (short8 or bf16x8 operands) ---
template <typename T>
__device__ __forceinline__ auto mfma_try(T a, T b, f32x4 c, int)
    -> decltype(__builtin_amdgcn_mfma_f32_16x16x32_bf16(a, b, c, 0, 0, 0)) {
    return __builtin_amdgcn_mfma_f32_16x16x32_bf16(a, b, c, 0, 0, 0);
}
template <typename T, typename U = b8v>
__device__ __forceinline__ f32x4 mfma_try(T a, T b, f32x4 c, long) {
    U ab = __builtin_bit_cast(U, a);
    U bb = __builtin_bit_cast(U, b);
    return __builtin_amdgcn_mfma_f32_16x16x32_bf16(ab, bb, c, 0, 0, 0);
}
__device__ __forceinline__ f32x4 mfma16x16x32_bf16(s8v a, s8v b, f32x4 c) {
    return mfma_try(a, b, c, 0);
}

__device__ __forceinline__ float bf2f(__hip_bfloat16 h) { return __bfloat162float(h); }

__device__ __forceinline__ float tanh_fast(float x) {
    // tanh(x) = 1 - 2/(exp(2x)+1); exp->inf -> rcp=0 -> 1; exp->0 -> -1; tanh(0)=0 exact.
    float e = __expf(2.f * x);
    return 1.f - 2.f * __builtin_amdgcn_rcpf(e + 1.f);
}

// ---------- dtype detection (wave-parallel: ~5 loads/lane, ballot reduce) ----------
__global__ void detect_dtypes(const unsigned int* __restrict__ emb_raw,
                              const unsigned int* __restrict__ ids_raw,
                              int* __restrict__ flags) {
    const int lane = threadIdx.x;   // 64 threads, 1 block
    int f32 = 0;
    #pragma unroll
    for (int rep = 0; rep < 4; rep++) {
        unsigned int w = emb_raw[lane + rep * 64];
        unsigned int e0 = (w >> 7)  & 0xFF;
        unsigned int e1 = (w >> 23) & 0xFF;
        if (e0 >= 0x87 || e1 >= 0x87) f32 = 1;   // |x| >= 256 impossible for real data
    }
    unsigned long long mf = __ballot(f32 != 0);
    unsigned long long mz = __ballot(ids_raw[2 * lane + 1] == 0u);
    if (lane == 0) {
        flags[0] = mf ? 1 : 0;
        flags[1] = (__popcll(mz) >= 32) ? 1 : 0;
    }
}

// ---------- canonicalize weights into zero-padded bf16 tiles in workspace ----------
// ht feature axis packed: k<112 -> head feature k (k<100, else 0);
//                         k>=112 -> tail feature k-112 ((k-112)<100, else 0).
// The zero pads absorb the fused kernel's branchless LDS over-reads.
__global__ void prep_weights(const void* __restrict__ Wht, const void* __restrict__ bht,
                             const void* __restrict__ Wrl, const void* __restrict__ brl,
                             void* __restrict__ ws) {
    const int* flags = (const int*)ws;
    const bool f32 = flags[0] != 0;
    __hip_bfloat16* whtp = (__hip_bfloat16*)((char*)ws + WS_WHT);
    __hip_bfloat16* wrlp = (__hip_bfloat16*)((char*)ws + WS_WRL);
    __hip_bfloat16* bhtp = (__hip_bfloat16*)((char*)ws + WS_BHT);
    __hip_bfloat16* brlp = (__hip_bfloat16*)((char*)ws + WS_BRL);

    const int gid = blockIdx.x * blockDim.x + threadIdx.x;
    const int gs  = gridDim.x * blockDim.x;

    for (int i = gid; i < DPAD * KHT; i += gs) {
        int d = i / KHT, f = i - d * KHT;
        int src = -1;
        if (f < 112) { if (f < DD) src = f; }                // head region
        else { int t = f - 112; if (t < DD) src = DD + t; }  // tail region
        float v = 0.f;
        if (d < DD && src >= 0)
            v = f32 ? ((const float*)Wht)[d * TWO_D + src]
                    : bf2f(((const __hip_bfloat16*)Wht)[d * TWO_D + src]);
        whtp[i] = __float2bfloat16(v);
    }
    for (int i = gid; i < DPAD * KRL; i += gs) {
        int d = i / KRL, f = i - d * KRL;
        float v = 0.f;
        if (d < DD && f < DD)
            v = f32 ? ((const float*)Wrl)[d * DD + f]
                    : bf2f(((const __hip_bfloat16*)Wrl)[d * DD + f]);
        wrlp[i] = __float2bfloat16(v);
    }
    for (int i = gid; i < DPAD; i += gs) {
        float vh = 0.f, vr = 0.f;
        if (i < DD) {
            vh = f32 ? ((const float*)bht)[i] : bf2f(((const __hip_bfloat16*)bht)[i]);
            vr = f32 ? ((const float*)brl)[i] : bf2f(((const __hip_bfloat16*)brl)[i]);
        }
        bhtp[i] = __float2bfloat16(vh);
        brlp[i] = __float2bfloat16(vr);
    }
}

// ---------- batched gather: issue CNT independent loads, THEN write LDS ----------
// chunk c: row seg = c/25 (= triple*3 + {0=h,1=r,2=t}), elem off = (c%25)*4.
// LDS dst elem = seg*ROWP + off. doff<0 = skip (tail lanes).
template <int CNT>
__device__ __forceinline__ void gather_f32(const float* __restrict__ embf,
                                           const int* __restrict__ sIds,
                                           __hip_bfloat16* sX, int tid, int base) {
    float4 v[CNT];
    int doff[CNT];
    #pragma unroll
    for (int i = 0; i < CNT; ++i) {
        int c = tid + (base + i) * 256;
        bool ok = (c < NCHUNK);
        int cc = ok ? c : 0;
        int seg = cc / 25;
        int off = (cc - seg * 25) * 4;
        size_t id = (size_t)sIds[seg];
        v[i] = *(const float4*)(embf + id * DD + off);   // 16B aligned (row = 400B)
        doff[i] = ok ? (seg * ROWP + off) : -1;
    }
    #pragma unroll
    for (int i = 0; i < CNT; ++i) {
        if (doff[i] >= 0) {
            b4v pk = { (__bf16)v[i].x, (__bf16)v[i].y, (__bf16)v[i].z, (__bf16)v[i].w };
            *(b4v*)(sX + doff[i]) = pk;              // 8B aligned (ROWP*2=208, off*2%8==0)
        }
    }
}

template <int CNT>
__device__ __forceinline__ void gather_bf16(const __hip_bfloat16* __restrict__ embh,
                                            const int* __restrict__ sIds,
                                            __hip_bfloat16* sX, int tid, int base) {
    uint2 v[CNT];
    int doff[CNT];
    #pragma unroll
    for (int i = 0; i < CNT; ++i) {
        int c = tid + (base + i) * 256;
        bool ok = (c < NCHUNK);
        int cc = ok ? c : 0;
        int seg = cc / 25;
        int off = (cc - seg * 25) * 4;
        size_t id = (size_t)sIds[seg];
        v[i] = *(const uint2*)(embh + id * DD + off);    // 8B aligned (row = 200B)
        doff[i] = ok ? (seg * ROWP + off) : -1;
    }
    #pragma unroll
    for (int i = 0; i < CNT; ++i) {
        if (doff[i] >= 0) *(uint2*)(sX + doff[i]) = v[i];
    }
}

// ---------- one d-tile pass: NTP tiles of 16 features starting at ntBase ----------
// Accumulates dj[j] += (rel+b_rl) * tanh(ht+b_ht) for this pass's features.
// Peak live accumulators: 2*NTP*4 (<= 32 regs at NTP=4).
template <int NTP>
__device__ __forceinline__ void gemm_pass(
    const __hip_bfloat16* __restrict__ sX,
    const __hip_bfloat16* __restrict__ whtp, const __hip_bfloat16* __restrict__ wrlp,
    const __hip_bfloat16* __restrict__ bhtp, const __hip_bfloat16* __restrict__ brlp,
    int hbase, int n, int q, int ntBase, float dj[4]) {

    f32x4 accH[NTP];
    #pragma unroll
    for (int t = 0; t < NTP; t++) {
        #pragma unroll
        for (int j = 0; j < 4; j++) accH[t][j] = 0.f;
    }
    // ht GEMM: K=224 packed [head 112 | tail 112]; chunk c=ks*4+q.
    // c<14 -> head elems c*8.. ; c>=14 -> tail elems (c-14)*8..
    // Over-reads past elem 100 hit finite bytes (pads zeroed / next row / dummy
    // row) and multiply W's zero pad columns -> contribute 0. Branchless.
    #pragma unroll
    for (int ks = 0; ks < 7; ks++) {
        const int  c    = ks * 4 + q;
        const bool ish  = (c < 14);
        const int  eoff = ish ? (hbase + c * 8) : (hbase + 2 * ROWP + (c - 14) * 8);
        s8v a = *(const s8v*)(sX + eoff);
        #pragma unroll
        for (int nt = 0; nt < NTP; nt++) {
            s8v b = *(const s8v*)(whtp + ((ntBase + nt) * 16 + n) * KHT + ks * 32 + q * 8);
            accH[nt] = mfma16x16x32_bf16(a, b, accH[nt]);
        }
    }

    f32x4 accR[NTP];
    #pragma unroll
    for (int t = 0; t < NTP; t++) {
        #pragma unroll
        for (int j = 0; j < 4; j++) accR[t][j] = 0.f;
    }
    // rel GEMM: K=128; rel row at hbase+ROWP; c=ks*4+q in [0,16).
    // c>=13 over-reads into tail row (finite) x W-zeros -> 0. Branchless.
    #pragma unroll
    for (int ks = 0; ks < 4; ks++) {
        const int c = ks * 4 + q;
        s8v a = *(const s8v*)(sX + hbase + ROWP + c * 8);
        #pragma unroll
        for (int nt = 0; nt < NTP; nt++) {
            s8v b = *(const s8v*)(wrlp + ((ntBase + nt) * 16 + n) * KRL + ks * 32 + q * 8);
            accR[nt] = mfma16x16x32_bf16(a, b, accR[nt]);
        }
    }

    // combine (deferred tanh): padded d -> acc=0,bias=0 -> 0 contribution
    #pragma unroll
    for (int nt = 0; nt < NTP; nt++) {
        const float bh = bf2f(bhtp[(ntBase + nt) * 16 + n]);
        const float br = bf2f(brlp[(ntBase + nt) * 16 + n]);
        #pragma unroll
        for (int j = 0; j < 4; j++)
            dj[j] += (accR[nt][j] + br) * tanh_fast(accH[nt][j] + bh);
    }
}

__global__ __launch_bounds__(256, 5) void fused_outer_encoder(
    const int* __restrict__ ids,              // int32 or int64 (flagged)
    const void* __restrict__ emb_raw,         // fp32 or bf16 (flagged), [V][DD]
    const void* __restrict__ ws,
    float* __restrict__ out)                  // [NBT][TWO_D] fp32
{
    __shared__ __hip_bfloat16 sX[SX_ELEMS];   // 151 rows x 104 elems = 31408 B
    __shared__ int   sIds[KK * 3];
    __shared__ float sE[64];
    __shared__ float sAl[KK];

    const int* flags = (const int*)ws;
    const __hip_bfloat16* whtp = (const __hip_bfloat16*)((const char*)ws + WS_WHT);
    const __hip_bfloat16* wrlp = (const __hip_bfloat16*)((const char*)ws + WS_WRL);
    const __hip_bfloat16* bhtp = (const __hip_bfloat16*)((const char*)ws + WS_BHT);
    const __hip_bfloat16* brlp = (const __hip_bfloat16*)((const char*)ws + WS_BRL);

    const int tid = threadIdx.x;
    const int bt  = blockIdx.x;
    const bool f32      = flags[0] != 0;
    const int idsStride = flags[1] ? 2 : 1;   // int64: read low word

    // ---- issue ids load first (latency overlaps the pad-zeroing stores) ----
    int myid = 0;
    if (tid < NROWS) myid = ids[(bt * NROWS + tid) * idsStride];

    // ---- zero the 4-elem row pads (NaN-bit safety for chunk over-reads) and
    //      the dummy row 150 (overrun target of row 149). 8B stores. ----
    for (int i = tid; i < 176; i += 256) {
        if (i < 151) *(uint2*)((char*)sX + i * (ROWP * 2) + 200) = make_uint2(0u, 0u);
        else         *(uint2*)((char*)sX + NROWS * (ROWP * 2) + (i - 151) * 8) = make_uint2(0u, 0u);
    }
    if (tid < NROWS) sIds[tid] = myid;
    __syncthreads();

    // ---- gather emb rows -> LDS bf16; 15 chunks/thread in 8+7 deep batches ----
    if (f32) {
        const float* embf = (const float*)emb_raw;
        gather_f32<8>(embf, sIds, sX, tid, 0);
        gather_f32<7>(embf, sIds, sX, tid, 8);
    } else {
        const __hip_bfloat16* embh = (const __hip_bfloat16*)emb_raw;
        gather_bf16<8>(embh, sIds, sX, tid, 0);
        gather_bf16<7>(embh, sIds, sX, tid, 8);
    }
    __syncthreads();

    const int lane = tid & 63;
    const int w    = tid >> 6;        // wave id: triples [w*16, w*16+16)
    const int n    = lane & 15;       // A row (triple) / B col (feature) selector
    const int q    = lane >> 4;       // quad: k-slice q*8 within each 32-k window
    const int arow = w * 16 + n;
    const int arc  = (arow < KK) ? arow : 0;   // clamp: C rows >= KK are discarded
    const int hbase = 3 * arc * ROWP;          // head row base (elems)

    // ---- two d-tile passes (4 + 3) keep peak accumulators at 32 regs ----
    float dj[4] = {0.f, 0.f, 0.f, 0.f};
    gemm_pass<4>(sX, whtp, wrlp, bhtp, brlp, hbase, n, q, 0, dj);
    gemm_pass<3>(sX, whtp, wrlp, bhtp, brlp, hbase, n, q, 4, dj);

    // ---- reduce over the 16 n-lanes (feature dim) of each quad ----
    #pragma unroll
    for (int mask = 1; mask < 16; mask <<= 1) {
        #pragma unroll
        for (int j = 0; j < 4; j++) dj[j] += __shfl_xor(dj[j], mask, 64);
    }
    if (n == 0) {
        #pragma unroll
        for (int j = 0; j < 4; j++) {
            const int kt = w * 16 + q * 4 + j;   // C/D row = quad*4 + reg
            if (kt < KK) sE[kt] = dj[j];
        }
    }
    __syncthreads();

    // ---- softmax over KK triples (wave 0) ----
    if (tid < 64) {
        float v = (tid < KK) ? sE[tid] : -3.0e38f;
        float mx = v;
        #pragma unroll
        for (int mask = 1; mask < 64; mask <<= 1) mx = fmaxf(mx, __shfl_xor(mx, mask, 64));
        float p = (tid < KK) ? __expf(v - mx) : 0.f;
        float s = p;
        #pragma unroll
        for (int mask = 1; mask < 64; mask <<= 1) s += __shfl_xor(s, mask, 64);
        if (tid < KK) sAl[tid] = p / s;
    }
    __syncthreads();

    // ---- output (fp32): out[bt][d] = sum_k alpha[k] * head_tail[k][d] ----
    // Re-gather from global emb in full fp32 precision (rows are L2-hot: this
    // block just staged them). d<100 -> head row, d>=100 -> tail row.
    if (tid < TWO_D) {
        const int half  = tid / DD;            // 0=head, 1=tail
        const int dmod  = tid - half * DD;
        const int whoff = half ? 2 : 0;
        float acc = 0.f;
        if (f32) {
            const float* embf = (const float*)emb_raw;
            #pragma unroll 10
            for (int k = 0; k < KK; k++) {
                size_t id = (size_t)sIds[k * 3 + whoff];
                acc += sAl[k] * embf[id * DD + dmod];
            }
        } else {
            const __hip_bfloat16* embh = (const __hip_bfloat16*)emb_raw;
            #pragma unroll 10
            for (int k = 0; k < KK; k++) {
                size_t id = (size_t)sIds[k * 3 + whoff];
                acc += sAl[k] * bf2f(embh[id * DD + dmod]);
            }
        }
        out[(size_t)bt * TWO_D + tid] = acc;
    }
}

extern "C" void kernel_launch(void* const* d_in, const int* in_sizes, int n_in,
                              void* d_out, int out_size, void* d_ws, size_t ws_size,
                              hipStream_t stream) {
    const int*  ids = (const int*)d_in[1];
    const void* emb = d_in[3];
    const void* Wht = d_in[4];
    const void* bht = d_in[5];
    const void* Wrl = d_in[6];
    const void* brl = d_in[7];
    float* out = (float*)d_out;

    const int nbt = in_sizes[1] / (KK * 3);   // B*T blocks

    hipLaunchKernelGGL(detect_dtypes, dim3(1), dim3(64), 0, stream,
                       (const unsigned int*)emb, (const unsigned int*)ids, (int*)d_ws);
    hipLaunchKernelGGL(prep_weights, dim3(64), dim3(256), 0, stream,
                       Wht, bht, Wrl, brl, d_ws);
    hipLaunchKernelGGL(fused_outer_encoder, dim3(nbt), dim3(256), 0, stream,
                       ids, emb, (const void*)d_ws, out);
}

// Round 7
// 466.577 us; speedup vs baseline: 1.1327x; 1.0983x over previous
//
#include <hip/hip_runtime.h>
#include <hip/hip_bf16.h>

#define KK 50      // triples per (b,t)
#define DD 100
#define TWO_D 200
#define DPAD 112   // padded output-feature dim (7 * 16)
#define KHT 224    // padded K for head_tail gemm: [head pad 112 | tail pad 112]
#define KRL 128    // padded K for relation gemm (4 * 32)

#define NROWS 150  // 50 triples * {head, rel, tail}
#define ROWP 120   // LDS row pitch (bf16 elems) = 240 B; over-reads stay wave-private,
                   // A-read bank stride 180 dw -> 8 bank-sets -> free 2-way conflicts
#define SX_ELEMS (NROWS * ROWP)   // 18000 elems = 36000 B

// workspace layout (bytes)
#define WS_FLAGS 0
#define WS_WHT 256                       // bf16[DPAD*KHT]  = 50176 B
#define WS_WRL (WS_WHT + DPAD*KHT*2)     // bf16[DPAD*KRL]  = 28672 B
#define WS_BHT (WS_WRL + DPAD*KRL*2)     // bf16[DPAD] (256 B slot)
#define WS_BRL (WS_BHT + 256)

typedef __attribute__((ext_vector_type(8))) short   s8v;
typedef __attribute__((ext_vector_type(8))) __bf16  b8v;
typedef __attribute__((ext_vector_type(4))) __bf16  b4v;
typedef __attribute__((ext_vector_type(4))) float   f32x4;

// --- MFMA shim: tolerate either builtin signature (short8 or bf16x8 operands) ---
template <typename T>
__device__ __forceinline__ auto mfma_try(T a, T b, f32x4 c, int)
    -> decltype(__builtin_amdgcn_mfma_f32_16x16x32_bf16(a, b, c, 0, 0, 0)) {
    return __builtin_amdgcn_mfma_f32_16x16x32_bf16(a, b, c, 0, 0, 0);
}
template <typename T, typename U = b8v>
__device__ __forceinline__ f32x4 mfma_try(T a, T b, f32x4 c, long) {
    U ab = __builtin_bit_cast(U, a);
    U bb = __builtin_bit_cast(U, b);
    return __builtin_amdgcn_mfma_f32_16x16x32_bf16(ab, bb, c, 0, 0, 0);
}
__device__ __forceinline__ f32x4 mfma16x16x32_bf16(s8v a, s8v b, f32x4 c) {
    return mfma_try(a, b, c, 0);
}

__device__ __forceinline__ float bf2f(__hip_bfloat16 h) { return __bfloat162float(h); }

__device__ __forceinline__ float tanh_fast(float x) {
    // tanh(x) = 1 - 2/(exp(2x)+1); exp->inf -> rcp=0 -> 1; exp->0 -> -1; tanh(0)=0 exact.
    float e = __expf(2.f * x);
    return 1.f - 2.f * __builtin_amdgcn_rcpf(e + 1.f);
}

// ---------- dtype detection (wave-parallel: ~5 loads/lane, ballot reduce) ----------
__global__ void detect_dtypes(const unsigned int* __restrict__ emb_raw,
                              const unsigned int* __restrict__ ids_raw,
                              int* __restrict__ flags) {
    const int lane = threadIdx.x;   // 64 threads, 1 block
    int f32 = 0;
    #pragma unroll
    for (int rep = 0; rep < 4; rep++) {
        unsigned int w = emb_raw[lane + rep * 64];
        unsigned int e0 = (w >> 7)  & 0xFF;
        unsigned int e1 = (w >> 23) & 0xFF;
        if (e0 >= 0x87 || e1 >= 0x87) f32 = 1;   // |x| >= 256 impossible for real data
    }
    unsigned long long mf = __ballot(f32 != 0);
    unsigned long long mz = __ballot(ids_raw[2 * lane + 1] == 0u);
    if (lane == 0) {
        flags[0] = mf ? 1 : 0;
        flags[1] = (__popcll(mz) >= 32) ? 1 : 0;
    }
}

// ---------- canonicalize weights into zero-padded bf16 tiles in workspace ----------
// ht feature axis packed: k<112 -> head feature k (k<100, else 0);
//                         k>=112 -> tail feature k-112 ((k-112)<100, else 0).
// Zero pads absorb the fused kernel's branchless LDS over-reads.
__global__ void prep_weights(const void* __restrict__ Wht, const void* __restrict__ bht,
                             const void* __restrict__ Wrl, const void* __restrict__ brl,
                             void* __restrict__ ws) {
    const int* flags = (const int*)ws;
    const bool f32 = flags[0] != 0;
    __hip_bfloat16* whtp = (__hip_bfloat16*)((char*)ws + WS_WHT);
    __hip_bfloat16* wrlp = (__hip_bfloat16*)((char*)ws + WS_WRL);
    __hip_bfloat16* bhtp = (__hip_bfloat16*)((char*)ws + WS_BHT);
    __hip_bfloat16* brlp = (__hip_bfloat16*)((char*)ws + WS_BRL);

    const int gid = blockIdx.x * blockDim.x + threadIdx.x;
    const int gs  = gridDim.x * blockDim.x;

    for (int i = gid; i < DPAD * KHT; i += gs) {
        int d = i / KHT, f = i - d * KHT;
        int src = -1;
        if (f < 112) { if (f < DD) src = f; }                // head region
        else { int t = f - 112; if (t < DD) src = DD + t; }  // tail region
        float v = 0.f;
        if (d < DD && src >= 0)
            v = f32 ? ((const float*)Wht)[d * TWO_D + src]
                    : bf2f(((const __hip_bfloat16*)Wht)[d * TWO_D + src]);
        whtp[i] = __float2bfloat16(v);
    }
    for (int i = gid; i < DPAD * KRL; i += gs) {
        int d = i / KRL, f = i - d * KRL;
        float v = 0.f;
        if (d < DD && f < DD)
            v = f32 ? ((const float*)Wrl)[d * DD + f]
                    : bf2f(((const __hip_bfloat16*)Wrl)[d * DD + f]);
        wrlp[i] = __float2bfloat16(v);
    }
    for (int i = gid; i < DPAD; i += gs) {
        float vh = 0.f, vr = 0.f;
        if (i < DD) {
            vh = f32 ? ((const float*)bht)[i] : bf2f(((const __hip_bfloat16*)bht)[i]);
            vr = f32 ? ((const float*)brl)[i] : bf2f(((const __hip_bfloat16*)brl)[i]);
        }
        bhtp[i] = __float2bfloat16(vh);
        brlp[i] = __float2bfloat16(vr);
    }
}

// ---------- per-WAVE batched gather: issue CNT independent loads, THEN write LDS ----
// Wave-local chunk cw = lane + (base+i)*64 over tc = nrows*25 4-elem chunks.
// Row = rbase + cw/25, elem off = (cw%25)*4. doff<0 = skip (tail lanes).
template <int CNT>
__device__ __forceinline__ void gatherw_f32(const float* __restrict__ embf,
                                            const int* __restrict__ sIds,
                                            __hip_bfloat16* __restrict__ sX,
                                            int lane, int rbase, int tc, int base) {
    float4 v[CNT];
    int doff[CNT];
    #pragma unroll
    for (int i = 0; i < CNT; ++i) {
        int cw = lane + (base + i) * 64;
        bool ok = (cw < tc);
        int cc = ok ? cw : 0;
        int rr = cc / 25;
        int off = (cc - rr * 25) * 4;
        int row = rbase + rr;
        size_t id = (size_t)sIds[row];
        v[i] = *(const float4*)(embf + id * DD + off);   // 16B aligned (row = 400B)
        doff[i] = ok ? (row * ROWP + off) : -1;
    }
    #pragma unroll
    for (int i = 0; i < CNT; ++i) {
        if (doff[i] >= 0) {
            b4v pk = { (__bf16)v[i].x, (__bf16)v[i].y, (__bf16)v[i].z, (__bf16)v[i].w };
            *(b4v*)(sX + doff[i]) = pk;              // 8B aligned (240B pitch, off%4==0)
        }
    }
}

template <int CNT>
__device__ __forceinline__ void gatherw_bf16(const __hip_bfloat16* __restrict__ embh,
                                             const int* __restrict__ sIds,
                                             __hip_bfloat16* __restrict__ sX,
                                             int lane, int rbase, int tc, int base) {
    uint2 v[CNT];
    int doff[CNT];
    #pragma unroll
    for (int i = 0; i < CNT; ++i) {
        int cw = lane + (base + i) * 64;
        bool ok = (cw < tc);
        int cc = ok ? cw : 0;
        int rr = cc / 25;
        int off = (cc - rr * 25) * 4;
        int row = rbase + rr;
        size_t id = (size_t)sIds[row];
        v[i] = *(const uint2*)(embh + id * DD + off);    // 8B aligned (row = 200B)
        doff[i] = ok ? (row * ROWP + off) : -1;
    }
    #pragma unroll
    for (int i = 0; i < CNT; ++i) {
        if (doff[i] >= 0) *(uint2*)(sX + doff[i]) = v[i];
    }
}

// ---------- one d-tile pass: NTP tiles of 16 features starting at ntBase ----------
// dj[j] += (rel+b_rl) * tanh(ht+b_ht). Peak live accumulators 2*NTP*4 regs.
// hbase = head-row base elem offset of this lane's triple.
template <int NTP>
__device__ __forceinline__ void gemm_pass(
    const __hip_bfloat16* __restrict__ sX,
    const __hip_bfloat16* __restrict__ whtp, const __hip_bfloat16* __restrict__ wrlp,
    const __hip_bfloat16* __restrict__ bhtp, const __hip_bfloat16* __restrict__ brlp,
    int hbase, int n, int q, int ntBase, float dj[4]) {

    f32x4 accH[NTP];
    #pragma unroll
    for (int t = 0; t < NTP; t++) {
        #pragma unroll
        for (int j = 0; j < 4; j++) accH[t][j] = 0.f;
    }
    // ht GEMM: K=224 packed [head 112 | tail 112]; chunk c=ks*4+q.
    // c<14 -> head elems c*8 (max 111, intra-row, pads zeroed);
    // c>=14 -> tail elems (c-14)*8 (max 111, intra-row). Branchless + wave-private.
    #pragma unroll
    for (int ks = 0; ks < 7; ks++) {
        const int  c    = ks * 4 + q;
        const bool ish  = (c < 14);
        const int  eoff = ish ? (hbase + c * 8) : (hbase + 2 * ROWP + (c - 14) * 8);
        s8v a = *(const s8v*)(sX + eoff);
        #pragma unroll
        for (int nt = 0; nt < NTP; nt++) {
            s8v b = *(const s8v*)(whtp + ((ntBase + nt) * 16 + n) * KHT + ks * 32 + q * 8);
            accH[nt] = mfma16x16x32_bf16(a, b, accH[nt]);
        }
    }

    f32x4 accR[NTP];
    #pragma unroll
    for (int t = 0; t < NTP; t++) {
        #pragma unroll
        for (int j = 0; j < 4; j++) accR[t][j] = 0.f;
    }
    // rel GEMM: K=128; rel row at hbase+ROWP; c=ks*4+q in [0,16).
    // c=13,14 hit zeroed intra-row pads; c=15 over-reads into same triple's tail
    // row (wave-private, finite) x W-zero cols -> 0. Branchless.
    #pragma unroll
    for (int ks = 0; ks < 4; ks++) {
        const int c = ks * 4 + q;
        s8v a = *(const s8v*)(sX + hbase + ROWP + c * 8);
        #pragma unroll
        for (int nt = 0; nt < NTP; nt++) {
            s8v b = *(const s8v*)(wrlp + ((ntBase + nt) * 16 + n) * KRL + ks * 32 + q * 8);
            accR[nt] = mfma16x16x32_bf16(a, b, accR[nt]);
        }
    }

    // combine (deferred tanh): padded d -> acc=0,bias=0 -> 0 contribution
    #pragma unroll
    for (int nt = 0; nt < NTP; nt++) {
        const float bh = bf2f(bhtp[(ntBase + nt) * 16 + n]);
        const float br = bf2f(brlp[(ntBase + nt) * 16 + n]);
        #pragma unroll
        for (int j = 0; j < 4; j++)
            dj[j] += (accR[nt][j] + br) * tanh_fast(accH[nt][j] + bh);
    }
}

__global__ __launch_bounds__(256, 4) void fused_outer_encoder(
    const int* __restrict__ ids,              // int32 or int64 (flagged)
    const void* __restrict__ emb_raw,         // fp32 or bf16 (flagged), [V][DD]
    const void* __restrict__ ws,
    float* __restrict__ out)                  // [NBT][TWO_D] fp32
{
    __shared__ __hip_bfloat16 sX[SX_ELEMS];   // 150 x 120 elems = 36000 B
    __shared__ int   sIds[NROWS];
    __shared__ float sE[64];
    __shared__ float sAl[KK];

    const int* flags = (const int*)ws;
    const __hip_bfloat16* whtp = (const __hip_bfloat16*)((const char*)ws + WS_WHT);
    const __hip_bfloat16* wrlp = (const __hip_bfloat16*)((const char*)ws + WS_WRL);
    const __hip_bfloat16* bhtp = (const __hip_bfloat16*)((const char*)ws + WS_BHT);
    const __hip_bfloat16* brlp = (const __hip_bfloat16*)((const char*)ws + WS_BRL);

    const int tid = threadIdx.x;
    const int bt  = blockIdx.x;
    const bool f32      = flags[0] != 0;
    const int idsStride = flags[1] ? 2 : 1;   // int64: read low word

    const int lane  = tid & 63;
    const int w     = tid >> 6;
    // triples per wave: 13,13,12,12 (sums to 50). Wave w owns triples
    // [tbase, tbase+ntrip) == rows [rbase, rbase+nrows). Gather AND compute
    // are wave-private -> NO barrier between them (program-order lgkmcnt only).
    const int tbase = (w < 2) ? w * 13 : 26 + (w - 2) * 12;
    const int ntrip = (w < 2) ? 13 : 12;
    const int rbase = 3 * tbase;
    const int nrows = 3 * ntrip;
    const int tc    = nrows * 25;

    // ---- this wave's ids (one per lane) ----
    if (lane < nrows)
        sIds[rbase + lane] = ids[(bt * NROWS + rbase + lane) * idsStride];

    // ---- zero this wave's row pads, elems [100,120) = 5 x 8B per row ----
    for (int i = lane; i < nrows * 5; i += 64) {
        int rr = i / 5, p = i - rr * 5;
        *(uint2*)((char*)sX + (rbase + rr) * (ROWP * 2) + 200 + 8 * p) = make_uint2(0u, 0u);
    }

    // ---- wave-private gather: 39/36 rows, 8+8 deep batches, no barrier ----
    if (f32) {
        const float* embf = (const float*)emb_raw;
        gatherw_f32<8>(embf, sIds, sX, lane, rbase, tc, 0);
        gatherw_f32<8>(embf, sIds, sX, lane, rbase, tc, 8);
    } else {
        const __hip_bfloat16* embh = (const __hip_bfloat16*)emb_raw;
        gatherw_bf16<8>(embh, sIds, sX, lane, rbase, tc, 0);
        gatherw_bf16<8>(embh, sIds, sX, lane, rbase, tc, 8);
    }

    // ---- straight into GEMM (same-wave LDS dependence only) ----
    const int n = lane & 15;          // A row (triple-within-wave) / B col selector
    const int q = lane >> 4;          // quad: k-slice q*8 within each 32-k window
    const int arcn  = (n < ntrip) ? n : (ntrip - 1);    // clamp to gathered range
    const int hbase = (rbase + 3 * arcn) * ROWP;        // head row base (elems)

    float dj[4] = {0.f, 0.f, 0.f, 0.f};
    gemm_pass<4>(sX, whtp, wrlp, bhtp, brlp, hbase, n, q, 0, dj);
    gemm_pass<3>(sX, whtp, wrlp, bhtp, brlp, hbase, n, q, 4, dj);

    // ---- reduce over the 16 n-lanes (feature dim) of each quad ----
    #pragma unroll
    for (int mask = 1; mask < 16; mask <<= 1) {
        #pragma unroll
        for (int j = 0; j < 4; j++) dj[j] += __shfl_xor(dj[j], mask, 64);
    }
    if (n == 0) {
        #pragma unroll
        for (int j = 0; j < 4; j++) {
            const int m = q * 4 + j;             // C/D row = quad*4 + reg
            if (m < ntrip) sE[tbase + m] = dj[j];
        }
    }
    __syncthreads();

    // ---- softmax over KK triples (wave 0) ----
    if (tid < 64) {
        float v = (tid < KK) ? sE[tid] : -3.0e38f;
        float mx = v;
        #pragma unroll
        for (int mask = 1; mask < 64; mask <<= 1) mx = fmaxf(mx, __shfl_xor(mx, mask, 64));
        float p = (tid < KK) ? __expf(v - mx) : 0.f;
        float s = p;
        #pragma unroll
        for (int mask = 1; mask < 64; mask <<= 1) s += __shfl_xor(s, mask, 64);
        if (tid < KK) sAl[tid] = p / s;
    }
    __syncthreads();

    // ---- output (fp32): out[bt][d] = sum_k alpha[k] * head_tail[k][d] ----
    // Re-gather from global emb in full fp32 precision (rows are L2-hot: this
    // block just staged them). d<100 -> head row, d>=100 -> tail row.
    if (tid < TWO_D) {
        const int half  = tid / DD;            // 0=head, 1=tail
        const int dmod  = tid - half * DD;
        const int whoff = half ? 2 : 0;
        float acc = 0.f;
        if (f32) {
            const float* embf = (const float*)emb_raw;
            #pragma unroll 10
            for (int k = 0; k < KK; k++) {
                size_t id = (size_t)sIds[k * 3 + whoff];
                acc += sAl[k] * embf[id * DD + dmod];
            }
        } else {
            const __hip_bfloat16* embh = (const __hip_bfloat16*)emb_raw;
            #pragma unroll 10
            for (int k = 0; k < KK; k++) {
                size_t id = (size_t)sIds[k * 3 + whoff];
                acc += sAl[k] * bf2f(embh[id * DD + dmod]);
            }
        }
        out[(size_t)bt * TWO_D + tid] = acc;
    }
}

extern "C" void kernel_launch(void* const* d_in, const int* in_sizes, int n_in,
                              void* d_out, int out_size, void* d_ws, size_t ws_size,
                              hipStream_t stream) {
    const int*  ids = (const int*)d_in[1];
    const void* emb = d_in[3];
    const void* Wht = d_in[4];
    const void* bht = d_in[5];
    const void* Wrl = d_in[6];
    const void* brl = d_in[7];
    float* out = (float*)d_out;

    const int nbt = in_sizes[1] / NROWS;   // B*T blocks

    hipLaunchKernelGGL(detect_dtypes, dim3(1), dim3(64), 0, stream,
                       (const unsigned int*)emb, (const unsigned int*)ids, (int*)d_ws);
    hipLaunchKernelGGL(prep_weights, dim3(64), dim3(256), 0, stream,
                       Wht, bht, Wrl, brl, d_ws);
    hipLaunchKernelGGL(fused_outer_encoder, dim3(nbt), dim3(256), 0, stream,
                       ids, emb, (const void*)d_ws, out);
}